// Round 5
// baseline (119.019 us; speedup 1.0000x reference)
//
#include <hip/hip_runtime.h>

// NNLoss: bidirectional Chamfer NN-L1. B=16, N=M=2048, D=2, scalar f32 out.
//
// R15: ALGORITHMIC — x-sorted windowed NN (exact). R11-R14 post-mortem:
// four micro-rounds all within the ±1us harness noise band; brute-force
// O(N^2) (134M pairs @ ~0.12cyc/pair) is a local minimum at nn~21us.
// Gaussian data: NN dist ~0.03 sigma << x-extent => x-window pruning cuts
// pairs ~20x. Design:
//  K1 (32 blocks x 1024): bucket-sort each of 32 point-sets (16b x
//    {preds,targs}) by x into ws: recs[set][2048] = float4(x,y,idx,0),
//    bucketStart[set][129]. 128 buckets over [-5,5], w=0.078125 (exact).
//    Scatter order within bucket arbitrary (atomics) but GLOBAL (one ws
//    copy) => all K2 blocks see one consistent order.
//  K2 (1024 blocks x 256): 64 sorted queries/block, 4 lanes per query
//    (sub-lane strided scan, u64 shfl merge). Per wave: 16 adjacent
//    sorted queries => window = buckets spanning their x-range; scan is
//    broadcast-ish (4 distinct addrs/wave). EXACT ring extension: while
//    any lane's (dist to window x-edge - 1e-5 slack)^2 <= best d2, extend
//    window one bucket that side and scan it. u64 (d2bits<<32|orig_idx)
//    min = jnp first-index tie-break, order-independent. d2 =
//    fma(dx,dx,dy*dy) >= 0 so raw f32 bits are monotone.
//  Tail: matched point re-fetched from original tensor (L2-hot), L1 sum,
//  block reduce, atomicAdd onto poisoned d_out (as before, harmless).
// ws budget: 1MB recs + 16.5KB starts << 268MB (the 40us fill = ws poison
// => ws is 268MB; fully overwritten by K1 before K2 reads).
// Predicted: nn 21 -> ~8-11us => dur 73.3 -> ~60-64us, absmax 0.0.
// Fail modes: absmax>0 => bound bug; hang => extension loop; ~73 => ws/
// dispatch overhead (then fuse sort into K2).

typedef float v2f __attribute__((ext_vector_type(2)));

constexpr int   NPTS = 2048;
constexpr int   NB   = 128;            // x-buckets
constexpr float XMIN = -5.0f;          // |x|>5 clamped to edge buckets (safe)
constexpr float BW   = 0.078125f;      // 10/128, exact in fp32
constexpr float INVW = 12.8f;
constexpr float SLCK = 1e-5f;          // bucket-edge rounding slack

// ws layout
constexpr size_t RECS_OFF  = 0;                  // float4[32][2048] = 1 MB
constexpr size_t START_OFF = 32 * NPTS * 16;     // int[32][129]

__device__ __forceinline__ int xbucket(float x) {
    int bk = (int)((x - XMIN) * INVW);
    return bk < 0 ? 0 : (bk > NB - 1 ? NB - 1 : bk);
}

__device__ __forceinline__ unsigned long long shflx64(unsigned long long v, int m) {
    unsigned int lo = (unsigned int)v, hi = (unsigned int)(v >> 32);
    lo = __shfl_xor(lo, m, 64);
    hi = __shfl_xor(hi, m, 64);
    return ((unsigned long long)hi << 32) | lo;
}

// K1: bucket-sort one point-set per block. set s: tensor t=s>>4, batch b=s&15.
__global__ __launch_bounds__(1024) void build_sorted(
    const float* __restrict__ preds, const float* __restrict__ targs,
    float4* __restrict__ recs, int* __restrict__ gstart)
{
    __shared__ int cnt[NB];
    __shared__ int ofs[NB];
    __shared__ int wtot;

    const int s   = blockIdx.x;
    const int t   = s >> 4;
    const int b   = s & 15;
    const int tid = threadIdx.x;
    const float* src = (t == 0 ? preds : targs) + b * (NPTS * 2);

    if (tid < NB) cnt[tid] = 0;
    __syncthreads();

    // two points per thread via one float4
    const float4 f = reinterpret_cast<const float4*>(src)[tid];
    const int bk0 = xbucket(f.x);
    const int bk1 = xbucket(f.z);
    atomicAdd(&cnt[bk0], 1);
    atomicAdd(&cnt[bk1], 1);
    __syncthreads();

    // exclusive prefix over 128 counters (2-wave shfl scan)
    const int lane = tid & 63;
    int v = (tid < NB) ? cnt[tid] : 0;
    #pragma unroll
    for (int off = 1; off < 64; off <<= 1) {
        const int u = __shfl_up(v, off, 64);
        if (lane >= off) v += u;
    }
    if (tid == 63) wtot = v;
    __syncthreads();
    if (tid >= 64 && tid < NB) v += wtot;
    if (tid < NB) {
        const int ex = v - cnt[tid];
        ofs[tid] = ex;
        gstart[s * (NB + 1) + tid] = ex;
    }
    if (tid == 0) gstart[s * (NB + 1) + NB] = NPTS;
    __syncthreads();

    // scatter
    {
        const int p0 = atomicAdd(&ofs[bk0], 1);
        recs[s * NPTS + p0] = {f.x, f.y, __int_as_float(2 * tid), 0.0f};
        const int p1 = atomicAdd(&ofs[bk1], 1);
        recs[s * NPTS + p1] = {f.z, f.w, __int_as_float(2 * tid + 1), 0.0f};
    }
}

// K2: windowed exact NN. 64 sorted queries/block, 4 lanes per query.
__global__ __launch_bounds__(256) void nn_pruned(
    const float* __restrict__ preds, const float* __restrict__ targs,
    const float* __restrict__ subcoef, float* __restrict__ out,
    const float4* __restrict__ recs, const int* __restrict__ gstart)
{
    __shared__ int   st[NB + 1];
    __shared__ float ssum[4];

    const int blk = blockIdx.x;
    const int tid = threadIdx.x;
    const int dir  = blk >> 9;          // 0: preds->targs (subcoef), 1: reverse
    const int b    = (blk >> 5) & 15;
    const int tile = blk & 31;

    const int qset = (dir ? 16 : 0) + b;   // queries: dir0=preds(t0), dir1=targs(t1)
    const int dset = (dir ? 0 : 16) + b;

    if (tid <= NB) st[tid] = gstart[dset * (NB + 1) + tid];
    __syncthreads();

    const int qs  = tile * 64 + (tid >> 2);   // sorted query index
    const int sub = tid & 3;
    const float4 qr = recs[qset * NPTS + qs];
    const float qx = qr.x, qy = qr.y;

    // wave x-range of its 16 queries
    float xmn = qx, xmx = qx;
    #pragma unroll
    for (int m = 1; m < 64; m <<= 1) {
        xmn = fminf(xmn, __shfl_xor(xmn, m, 64));
        xmx = fmaxf(xmx, __shfl_xor(xmx, m, 64));
    }
    int blo = xbucket(xmn);
    int bhi = xbucket(xmx);

    const float4* P = recs + dset * NPTS;
    unsigned long long best = 0x7F800000FFFFFFFFull;   // +inf | max idx

    int jlo = st[blo];
    int jhi = st[bhi + 1];

    // scan [a,bnd) with stride 4 starting at sub
    #define SCAN(a, bnd)                                                        \
        for (int j = (a) + sub; j < (bnd); j += 4) {                            \
            const float4 r = P[j];                                              \
            const float dx = qx - r.x, dy = qy - r.y;                           \
            const float d2 = fmaf(dx, dx, dy * dy);                             \
            const unsigned long long pk =                                       \
                ((unsigned long long)__float_as_uint(d2) << 32) |               \
                (unsigned int)__float_as_int(r.z);                              \
            best = pk < best ? pk : best;                                       \
        }

    SCAN(jlo, jhi)

    // exact ring extension
    while (true) {
        unsigned long long o = shflx64(best, 1); best = o < best ? o : best;
        o = shflx64(best, 2);                    best = o < best ? o : best;
        const float bd = __uint_as_float((unsigned int)(best >> 32));
        const float lb = fmaxf(qx - fmaf((float)blo, BW, XMIN) - SLCK, 0.0f);
        const float rb = fmaxf(fmaf((float)(bhi + 1), BW, XMIN) - qx - SLCK, 0.0f);
        const bool nl = (blo > 0)      && (lb * lb <= bd);
        const bool nr = (bhi < NB - 1) && (rb * rb <= bd);
        const bool aL = __any(nl), aR = __any(nr);
        if (!aL && !aR) break;
        if (aL) { --blo; const int a = st[blo];      SCAN(a, jlo)   jlo = a; }
        if (aR) { ++bhi; const int e = st[bhi + 1];  SCAN(jhi, e)   jhi = e; }
    }
    #undef SCAN

    // L1 contribution (sub-lane 0 only; best already merged)
    float val = 0.0f;
    if (sub == 0) {
        const int idx = (int)(unsigned int)best;
        const float2* dbo = reinterpret_cast<const float2*>(dir ? preds : targs)
                            + b * NPTS;
        const float2 tp = dbo[idx];
        float sx = 1.0f, sy = 1.0f;
        if (dir == 0) { sx = subcoef[0]; sy = subcoef[1]; }
        val = fabsf(qx - tp.x) * sx + fabsf(qy - tp.y) * sy;
    }

    #pragma unroll
    for (int off = 32; off > 0; off >>= 1)
        val += __shfl_down(val, off, 64);
    if ((tid & 63) == 0) ssum[tid >> 6] = val;
    __syncthreads();
    if (tid == 0) {
        const float s2 = ssum[0] + ssum[1] + ssum[2] + ssum[3];
        atomicAdd(out, s2);   // device-scope: coherent across XCDs
    }
}

extern "C" void kernel_launch(void* const* d_in, const int* in_sizes, int n_in,
                              void* d_out, int out_size, void* d_ws, size_t ws_size,
                              hipStream_t stream) {
    const float* preds   = (const float*)d_in[0];
    const float* targs   = (const float*)d_in[1];
    const float* subcoef = (const float*)d_in[2];
    float* out = (float*)d_out;

    float4* recs = (float4*)((char*)d_ws + RECS_OFF);
    int*    gst  = (int*)((char*)d_ws + START_OFF);

    build_sorted<<<32, 1024, 0, stream>>>(preds, targs, recs, gst);
    nn_pruned<<<1024, 256, 0, stream>>>(preds, targs, subcoef, out, recs, gst);
}

// Round 6
// 88.759 us; speedup vs baseline: 1.3409x; 1.3409x over previous
//
#include <hip/hip_runtime.h>

// NNLoss: bidirectional Chamfer NN-L1. B=16, N=M=2048, D=2, scalar f32 out.
//
// R16: R15 post-mortem — exact windowed NN worked (absmax 0, 7M pairs vs
// 134M) but K2 ran 66.5us at VALUBusy 7.7%: per-lane scattered GLOBAL
// loads (L2/L3, 200-900cyc, cross-XCD) under a serial wave-uniform
// extension loop = latency-bound, ~4 effective waves/CU (Occ 13% time-avg,
// straggler-dominated). Work model right, latency model missing.
// Fix: move the db to the right memory level + amortize the loop:
//  - LDS-stage the whole sorted set (2048 x float4 = 32KB) per block;
//    scan hits LDS (~120cyc, 69TB/s). LDS 33KB -> 4 blocks/CU = 16
//    waves/CU hiding. Staging coalesced, L2-hot (recs = 1MB total).
//  - initial window +-1 bucket (NNdist ~0.03-0.05 < BW 0.078) so the
//    ring-extension loop (exactness guarantee, straggler source) runs
//    0-2 iters for ~90% of waves instead of 4-6.
//  - K1, semantics, tie-break (u64 d2bits|idx min), tail unchanged.
// Predicted: K2 66.5 -> ~9-13us, VALUBusy -> 35-50%, total 119 -> ~62-67.
// If K2<=12 but total 70+: attack K1/gaps. If K2>25: per-lane windows.

typedef float v2f __attribute__((ext_vector_type(2)));

constexpr int   NPTS = 2048;
constexpr int   NB   = 128;            // x-buckets
constexpr float XMIN = -5.0f;          // |x|>5 clamped to edge buckets (safe)
constexpr float BW   = 0.078125f;      // 10/128, exact in fp32
constexpr float INVW = 12.8f;
constexpr float SLCK = 1e-5f;          // bucket-edge rounding slack

// ws layout
constexpr size_t RECS_OFF  = 0;                  // float4[32][2048] = 1 MB
constexpr size_t START_OFF = 32 * NPTS * 16;     // int[32][129]

__device__ __forceinline__ int xbucket(float x) {
    int bk = (int)((x - XMIN) * INVW);
    return bk < 0 ? 0 : (bk > NB - 1 ? NB - 1 : bk);
}

__device__ __forceinline__ unsigned long long shflx64(unsigned long long v, int m) {
    unsigned int lo = (unsigned int)v, hi = (unsigned int)(v >> 32);
    lo = __shfl_xor(lo, m, 64);
    hi = __shfl_xor(hi, m, 64);
    return ((unsigned long long)hi << 32) | lo;
}

// K1: bucket-sort one point-set per block. set s: tensor t=s>>4, batch b=s&15.
__global__ __launch_bounds__(1024) void build_sorted(
    const float* __restrict__ preds, const float* __restrict__ targs,
    float4* __restrict__ recs, int* __restrict__ gstart)
{
    __shared__ int cnt[NB];
    __shared__ int ofs[NB];
    __shared__ int wtot;

    const int s   = blockIdx.x;
    const int t   = s >> 4;
    const int b   = s & 15;
    const int tid = threadIdx.x;
    const float* src = (t == 0 ? preds : targs) + b * (NPTS * 2);

    if (tid < NB) cnt[tid] = 0;
    __syncthreads();

    // two points per thread via one float4
    const float4 f = reinterpret_cast<const float4*>(src)[tid];
    const int bk0 = xbucket(f.x);
    const int bk1 = xbucket(f.z);
    atomicAdd(&cnt[bk0], 1);
    atomicAdd(&cnt[bk1], 1);
    __syncthreads();

    // exclusive prefix over 128 counters (2-wave shfl scan)
    const int lane = tid & 63;
    int v = (tid < NB) ? cnt[tid] : 0;
    #pragma unroll
    for (int off = 1; off < 64; off <<= 1) {
        const int u = __shfl_up(v, off, 64);
        if (lane >= off) v += u;
    }
    if (tid == 63) wtot = v;
    __syncthreads();
    if (tid >= 64 && tid < NB) v += wtot;
    if (tid < NB) {
        const int ex = v - cnt[tid];
        ofs[tid] = ex;
        gstart[s * (NB + 1) + tid] = ex;
    }
    if (tid == 0) gstart[s * (NB + 1) + NB] = NPTS;
    __syncthreads();

    // scatter
    {
        const int p0 = atomicAdd(&ofs[bk0], 1);
        recs[s * NPTS + p0] = {f.x, f.y, __int_as_float(2 * tid), 0.0f};
        const int p1 = atomicAdd(&ofs[bk1], 1);
        recs[s * NPTS + p1] = {f.z, f.w, __int_as_float(2 * tid + 1), 0.0f};
    }
}

// K2: windowed exact NN over LDS-staged sorted db. 64 queries/block,
// 4 lanes per query.
__global__ __launch_bounds__(256) void nn_pruned(
    const float* __restrict__ preds, const float* __restrict__ targs,
    const float* __restrict__ subcoef, float* __restrict__ out,
    const float4* __restrict__ recs, const int* __restrict__ gstart)
{
    __shared__ float4 pl[NPTS];        // 32 KB: whole sorted db set
    __shared__ int    st[NB + 1];
    __shared__ float  ssum[4];

    const int blk = blockIdx.x;
    const int tid = threadIdx.x;
    const int dir  = blk >> 9;          // 0: preds->targs (subcoef), 1: reverse
    const int b    = (blk >> 5) & 15;
    const int tile = blk & 31;

    const int qset = (dir ? 16 : 0) + b;   // queries: dir0=preds(t0), dir1=targs(t1)
    const int dset = (dir ? 0 : 16) + b;

    // Stage sorted db + bucket starts into LDS (coalesced, L2-hot).
    {
        const float4* P = recs + dset * NPTS;
        #pragma unroll
        for (int k = 0; k < NPTS / 256; ++k)
            pl[tid + k * 256] = P[tid + k * 256];
        if (tid <= NB) st[tid] = gstart[dset * (NB + 1) + tid];
    }

    const int qs  = tile * 64 + (tid >> 2);   // sorted query index
    const int sub = tid & 3;
    const float4 qr = recs[qset * NPTS + qs];
    const float qx = qr.x, qy = qr.y;

    // wave x-range of its 16 queries
    float xmn = qx, xmx = qx;
    #pragma unroll
    for (int m = 1; m < 64; m <<= 1) {
        xmn = fminf(xmn, __shfl_xor(xmn, m, 64));
        xmx = fmaxf(xmx, __shfl_xor(xmx, m, 64));
    }
    __syncthreads();

    // initial window: query span +-1 bucket (perf only; loop = exactness)
    int blo = xbucket(xmn) - 1; blo = blo < 0 ? 0 : blo;
    int bhi = xbucket(xmx) + 1; bhi = bhi > NB - 1 ? NB - 1 : bhi;

    unsigned long long best = 0x7F800000FFFFFFFFull;   // +inf | max idx

    int jlo = st[blo];
    int jhi = st[bhi + 1];

    // scan [a,bnd) with stride 4 starting at sub — LDS reads
    #define SCAN(a, bnd)                                                        \
        for (int j = (a) + sub; j < (bnd); j += 4) {                            \
            const float4 r = pl[j];                                             \
            const float dx = qx - r.x, dy = qy - r.y;                           \
            const float d2 = fmaf(dx, dx, dy * dy);                             \
            const unsigned long long pk =                                       \
                ((unsigned long long)__float_as_uint(d2) << 32) |               \
                (unsigned int)__float_as_int(r.z);                              \
            best = pk < best ? pk : best;                                       \
        }

    SCAN(jlo, jhi)

    // exact ring extension (rarely taken with the +-1 initial margin)
    while (true) {
        unsigned long long o = shflx64(best, 1); best = o < best ? o : best;
        o = shflx64(best, 2);                    best = o < best ? o : best;
        const float bd = __uint_as_float((unsigned int)(best >> 32));
        const float lb = fmaxf(qx - fmaf((float)blo, BW, XMIN) - SLCK, 0.0f);
        const float rb = fmaxf(fmaf((float)(bhi + 1), BW, XMIN) - qx - SLCK, 0.0f);
        const bool nl = (blo > 0)      && (lb * lb <= bd);
        const bool nr = (bhi < NB - 1) && (rb * rb <= bd);
        const bool aL = __any(nl), aR = __any(nr);
        if (!aL && !aR) break;
        if (aL) { --blo; const int a = st[blo];      SCAN(a, jlo)   jlo = a; }
        if (aR) { ++bhi; const int e = st[bhi + 1];  SCAN(jhi, e)   jhi = e; }
    }
    #undef SCAN

    // L1 contribution (sub-lane 0 only; best already merged)
    float val = 0.0f;
    if (sub == 0) {
        const int idx = (int)(unsigned int)best;
        const float2* dbo = reinterpret_cast<const float2*>(dir ? preds : targs)
                            + b * NPTS;
        const float2 tp = dbo[idx];
        float sx = 1.0f, sy = 1.0f;
        if (dir == 0) { sx = subcoef[0]; sy = subcoef[1]; }
        val = fabsf(qx - tp.x) * sx + fabsf(qy - tp.y) * sy;
    }

    #pragma unroll
    for (int off = 32; off > 0; off >>= 1)
        val += __shfl_down(val, off, 64);
    if ((tid & 63) == 0) ssum[tid >> 6] = val;
    __syncthreads();
    if (tid == 0) {
        const float s2 = ssum[0] + ssum[1] + ssum[2] + ssum[3];
        atomicAdd(out, s2);   // device-scope: coherent across XCDs
    }
}

extern "C" void kernel_launch(void* const* d_in, const int* in_sizes, int n_in,
                              void* d_out, int out_size, void* d_ws, size_t ws_size,
                              hipStream_t stream) {
    const float* preds   = (const float*)d_in[0];
    const float* targs   = (const float*)d_in[1];
    const float* subcoef = (const float*)d_in[2];
    float* out = (float*)d_out;

    float4* recs = (float4*)((char*)d_ws + RECS_OFF);
    int*    gst  = (int*)((char*)d_ws + START_OFF);

    build_sorted<<<32, 1024, 0, stream>>>(preds, targs, recs, gst);
    nn_pruned<<<1024, 256, 0, stream>>>(preds, targs, subcoef, out, recs, gst);
}

// Round 7
// 88.528 us; speedup vs baseline: 1.3444x; 1.0026x over previous
//
#include <hip/hip_runtime.h>

// NNLoss: bidirectional Chamfer NN-L1. B=16, N=M=2048, D=2, scalar f32 out.
//
// R17: FUSED single-kernel windowed NN. R16 post-mortem: K1+gap+K2 ~= 37us
// vs brute 21; healthy-scan model says ~6-10 => structure, not arithmetic:
// wave-uniform windows (union span + wave-wide extension stragglers),
// 33.5MB phase-synced recs re-fetch, 2-dispatch overhead, zero refill
// slack. Key insight: u64 (d2bits|origIdx) tie-break is ORDER-INDEPENDENT,
// so the global K1 sort was never needed -> sort block-locally in LDS.
// Design (one dispatch, no ws):
//  - 512 blocks (dir,b,tile) x 512 thr; 128 queries/block, 4 lanes/query;
//    2 blocks/CU (LDS ~34.5KB), 16 waves/CU.
//  - Phase A: block sorts its db set in LDS: raw 16KB coalesced -> regs,
//    128-bucket histogram (LDS atomics), 2-wave shfl prefix, scatter to
//    pl[2048] float4(x,y,idxf,0). Block-arbitrary in-bucket order is fine.
//  - Phase B: per-query window = own bucket +-1; SCAN strided sub=0..3;
//    group merge via shfl_xor 1,2 (stays in aligned 4-group); EXACT ring
//    extension per-group (qx, best, blo/bhi all group-uniform -> plain
//    divergent while, no ballots). Bound: (dist to window x-edge - SLCK)^2
//    <= best d2. Terminates at blo=0 && bhi=NB-1 worst case.
//  - Tail: sub==0 refetches matched point by ORIGINAL idx (L2-hot 8B),
//    L1 sum, wave+block reduce, 512 atomicAdds onto poisoned out (ok).
// Exactness: d2=fma(dx,dx,dy*dy)>=0 monotone bits; u64 min = first-index
// jnp tie-break via orig idx; clamped edge buckets safe (edge-dist <=
// point-dist); queries outside [-5,5] use raw qx in bounds.
// Predicted: kernel ~8-16us, total 88.8 -> ~62-68us, absmax 0.0.
// If >=73: windowed path dead on this harness -> revert to R11 brute.

constexpr int   NPTS = 2048;
constexpr int   NB   = 128;            // x-buckets
constexpr float XMIN = -5.0f;
constexpr float BW   = 0.078125f;      // 10/128, exact in fp32
constexpr float INVW = 12.8f;
constexpr float SLCK = 1e-5f;          // bucket-edge rounding slack

constexpr int BLK   = 512;
constexpr int QPB   = 128;             // queries per block (4 lanes each)
constexpr int TILES = NPTS / QPB;      // 16
constexpr int NBLK  = 2 * 16 * TILES;  // 512 blocks = 2 per CU

__device__ __forceinline__ int xbucket(float x) {
    int bk = (int)((x - XMIN) * INVW);
    return bk < 0 ? 0 : (bk > NB - 1 ? NB - 1 : bk);
}

__device__ __forceinline__ unsigned long long shflx64(unsigned long long v, int m) {
    unsigned int lo = (unsigned int)v, hi = (unsigned int)(v >> 32);
    lo = __shfl_xor(lo, m, 64);
    hi = __shfl_xor(hi, m, 64);
    return ((unsigned long long)hi << 32) | lo;
}

__global__ __launch_bounds__(BLK) void nn_fused(
    const float* __restrict__ preds, const float* __restrict__ targs,
    const float* __restrict__ subcoef, float* __restrict__ out)
{
    __shared__ float4 pl[NPTS];        // 32 KB sorted (x,y,idxf,0)
    __shared__ int    st[NB + 1];
    __shared__ int    cnt[NB];
    __shared__ int    ofs[NB];
    __shared__ int    wtot_s;
    __shared__ float  ssum[BLK / 64];

    const int blk = blockIdx.x;
    const int tid = threadIdx.x;
    const int dir  = blk >> 8;          // 0: preds->targs (subcoef), 1: reverse
    const int b    = (blk >> 4) & 15;
    const int tile = blk & 15;

    const float* qsrc = (dir == 0 ? preds : targs) + b * (NPTS * 2);
    const float* dsrc = (dir == 0 ? targs : preds) + b * (NPTS * 2);

    // ---- Phase A: block-local bucket sort of the db set ----
    if (tid < NB) cnt[tid] = 0;
    const float4* d4 = reinterpret_cast<const float4*>(dsrc);
    const float4 r0 = d4[tid];          // points 2*tid, 2*tid+1
    const float4 r1 = d4[tid + BLK];    // points 2*(tid+BLK), 2*(tid+BLK)+1
    __syncthreads();

    const int k0 = xbucket(r0.x), k1 = xbucket(r0.z);
    const int k2 = xbucket(r1.x), k3 = xbucket(r1.z);
    atomicAdd(&cnt[k0], 1);
    atomicAdd(&cnt[k1], 1);
    atomicAdd(&cnt[k2], 1);
    atomicAdd(&cnt[k3], 1);
    __syncthreads();

    // exclusive prefix over 128 counters (2-wave shfl scan)
    {
        const int lane = tid & 63;
        int v = (tid < NB) ? cnt[tid] : 0;
        #pragma unroll
        for (int off = 1; off < 64; off <<= 1) {
            const int u = __shfl_up(v, off, 64);
            if (lane >= off) v += u;
        }
        if (tid == 63) wtot_s = v;
        __syncthreads();
        if (tid >= 64 && tid < NB) v += wtot_s;
        if (tid < NB) {
            const int ex = v - cnt[tid];
            ofs[tid] = ex;
            st[tid]  = ex;
        }
        if (tid == 0) st[NB] = NPTS;
    }
    __syncthreads();

    {
        int p;
        p = atomicAdd(&ofs[k0], 1);
        pl[p] = {r0.x, r0.y, __int_as_float(2 * tid), 0.0f};
        p = atomicAdd(&ofs[k1], 1);
        pl[p] = {r0.z, r0.w, __int_as_float(2 * tid + 1), 0.0f};
        p = atomicAdd(&ofs[k2], 1);
        pl[p] = {r1.x, r1.y, __int_as_float(2 * (tid + BLK)), 0.0f};
        p = atomicAdd(&ofs[k3], 1);
        pl[p] = {r1.z, r1.w, __int_as_float(2 * (tid + BLK) + 1), 0.0f};
    }
    __syncthreads();

    // ---- Phase B: per-query (4-lane group) windowed exact NN ----
    const int qi  = tile * QPB + (tid >> 2);   // ORIGINAL query index
    const int sub = tid & 3;
    const float2 qp = reinterpret_cast<const float2*>(qsrc)[qi];
    const float qx = qp.x, qy = qp.y;

    int blo = xbucket(qx) - 1; blo = blo < 0 ? 0 : blo;
    int bhi = xbucket(qx) + 1; bhi = bhi > NB - 1 ? NB - 1 : bhi;

    unsigned long long best = 0x7F800000FFFFFFFFull;   // +inf | max idx
    int jlo = st[blo];
    int jhi = st[bhi + 1];

    #define SCAN(a, bnd)                                                        \
        for (int j = (a) + sub; j < (bnd); j += 4) {                            \
            const float4 r = pl[j];                                             \
            const float dx = qx - r.x, dy = qy - r.y;                           \
            const float d2 = fmaf(dx, dx, dy * dy);                             \
            const unsigned long long pk =                                       \
                ((unsigned long long)__float_as_uint(d2) << 32) |               \
                (unsigned int)__float_as_int(r.z);                              \
            best = pk < best ? pk : best;                                       \
        }

    SCAN(jlo, jhi)

    // exact ring extension, group-local (all controls group-uniform)
    while (true) {
        unsigned long long o = shflx64(best, 1); best = o < best ? o : best;
        o = shflx64(best, 2);                    best = o < best ? o : best;
        const float bd = __uint_as_float((unsigned int)(best >> 32));
        const float lb = fmaxf(qx - fmaf((float)blo, BW, XMIN) - SLCK, 0.0f);
        const float rb = fmaxf(fmaf((float)(bhi + 1), BW, XMIN) - qx - SLCK, 0.0f);
        const bool nl = (blo > 0)      && (lb * lb <= bd);
        const bool nr = (bhi < NB - 1) && (rb * rb <= bd);
        if (!nl && !nr) break;
        if (nl) { --blo; const int a = st[blo];      SCAN(a, jlo)   jlo = a; }
        if (nr) { ++bhi; const int e = st[bhi + 1];  SCAN(jhi, e)   jhi = e; }
    }
    #undef SCAN

    // L1 contribution (sub-lane 0; best already group-merged)
    float val = 0.0f;
    if (sub == 0) {
        const int idx = (int)(unsigned int)best;
        const float2 tp = reinterpret_cast<const float2*>(dsrc)[idx];
        float sx = 1.0f, sy = 1.0f;
        if (dir == 0) { sx = subcoef[0]; sy = subcoef[1]; }
        val = fabsf(qx - tp.x) * sx + fabsf(qy - tp.y) * sy;
    }

    #pragma unroll
    for (int off = 32; off > 0; off >>= 1)
        val += __shfl_down(val, off, 64);
    if ((tid & 63) == 0) ssum[tid >> 6] = val;
    __syncthreads();
    if (tid == 0) {
        float s = ssum[0];
        #pragma unroll
        for (int w = 1; w < BLK / 64; ++w) s += ssum[w];
        atomicAdd(out, s);   // device-scope: coherent across XCDs
    }
}

extern "C" void kernel_launch(void* const* d_in, const int* in_sizes, int n_in,
                              void* d_out, int out_size, void* d_ws, size_t ws_size,
                              hipStream_t stream) {
    const float* preds   = (const float*)d_in[0];
    const float* targs   = (const float*)d_in[1];
    const float* subcoef = (const float*)d_in[2];
    float* out = (float*)d_out;

    nn_fused<<<NBLK, BLK, 0, stream>>>(preds, targs, subcoef, out);
}

// Round 8
// 73.055 us; speedup vs baseline: 1.6292x; 1.2118x over previous
//
#include <hip/hip_runtime.h>

// NNLoss: bidirectional Chamfer NN-L1. B=16, N=M=2048, D=2, scalar f32 out.
//
// R18: REVERT to R11 (best measured: 72.70us this session). Windowed-NN
// path (R15-R17) is dead on this harness per pre-committed rule: exact
// (absmax 0) but 88.5-119us; its kernel pinned at ~36us across three
// structural variants (global vs LDS db, per-wave vs per-group windows,
// 2 vs 1 dispatches) with ~28us of stall mass invisible below the top-5
// counter cutoff. Brute anchor budget: ~52us harness-fixed (268MB ws
// poison fill @84% HBM + restores) + ~21us nn_main (scan ~4us VALU/DS;
// residual invariant to occupancy doubling per R14). R11-R14 micro-levers
// all within +-1us noise.
//
// R11 design: quad-packed LDS SoA (xs4/ys4) + precomputed t^2 (zs4, saves
// scan VALU), octet min-tracking (8 pts/tracked index), exact recovery by
// bit-identical recompute + first-match, u64 (d2bits|idx) cross-segment
// merge = jnp first-index argmin. Single dispatch; block partials
// atomicAdd onto poisoned d_out (harmless).

typedef float v2f __attribute__((ext_vector_type(2)));
typedef float v4f __attribute__((ext_vector_type(4)));

constexpr int B      = 16;
constexpr int NPTS   = 2048;
constexpr int BLK    = 1024;
constexpr int G      = 256;          // queries per block
constexpr int S      = 16;           // db segments (one per wave)
constexpr int QPT    = 4;            // queries per thread
constexpr int SEGLEN = NPTS / S;     // 128 points per segment
constexpr int QUADS  = SEGLEN / 4;   // 32 point-quads per segment
constexpr int OCTS   = SEGLEN / 8;   // 16 point-octets per segment
constexpr int NBLK   = 2 * B * (NPTS / G);  // 256 blocks

__global__ __launch_bounds__(BLK) void nn_main(
    const float* __restrict__ preds, const float* __restrict__ targs,
    const float* __restrict__ subcoef, float* __restrict__ out)
{
    __shared__ v4f xs4[NPTS / 4];                  // 8 KB quad-packed x
    __shared__ v4f ys4[NPTS / 4];                  // 8 KB quad-packed y
    __shared__ v4f zs4[NPTS / 4];                  // 8 KB quad-packed t^2
    __shared__ unsigned long long cand[S * G];     // 32 KB candidates
    __shared__ float ssum[BLK / 64];

    const int blk  = blockIdx.x;
    const int dir  = blk >> 7;          // 0: preds->targs (subcoef), 1: reverse
    const int b    = (blk >> 3) & 15;
    const int tile = blk & 7;

    const float2* qb = reinterpret_cast<const float2*>(dir == 0 ? preds : targs)
                       + b * NPTS + tile * G;
    const float2* db = reinterpret_cast<const float2*>(dir == 0 ? targs : preds)
                       + b * NPTS;

    // Stage db as quad-packed SoA. Threads <512 build xs4; >=512 build ys4
    // AND zs4 (t^2, fma-rounded exactly as recovery recomputes it).
    const float4* db4 = reinterpret_cast<const float4*>(db);
    {
        const int j = threadIdx.x & 511;
        const float4 a = db4[2 * j];
        const float4 c = db4[2 * j + 1];
        if (threadIdx.x < 512) {
            xs4[j] = {a.x, a.z, c.x, c.z};
        } else {
            ys4[j] = {a.y, a.w, c.y, c.w};
            zs4[j] = {fmaf(a.x, a.x, a.y * a.y), fmaf(a.z, a.z, a.w * a.w),
                      fmaf(c.x, c.x, c.y * c.y), fmaf(c.z, c.z, c.w * c.w)};
        }
    }

    const int qslot = threadIdx.x & 63;   // query slot within wave
    const int seg   = threadIdx.x >> 6;   // one 128-point segment per wave

    // 4 register-resident queries, coefficients splatted for packed fma.
    v2f   m2x[QPT], m2y[QPT];
    float best[QPT];
    int   bj[QPT];                        // best octet (0..15)
    #pragma unroll
    for (int q = 0; q < QPT; ++q) {
        const float2 qp = qb[qslot + q * 64];
        const float ax = -2.0f * qp.x, ay = -2.0f * qp.y;
        m2x[q] = {ax, ax};
        m2y[q] = {ay, ay};
        best[q] = 3.402823466e+38f;
        bj[q] = 0;
    }
    __syncthreads();

    // Scan segment, 8 points per super-iter. f(t) = t^2 - 2 q.t (monotone in
    // d^2 per query; bit-identical across segments -> exact cross-seg merge).
    const v4f* xsp = xs4 + seg * QUADS;
    const v4f* ysp = ys4 + seg * QUADS;
    const v4f* zsp = zs4 + seg * QUADS;
    #pragma unroll 2
    for (int i = 0; i < OCTS; ++i) {
        const v4f X0 = xsp[2 * i],     Y0 = ysp[2 * i],     Z0 = zsp[2 * i];
        const v4f X1 = xsp[2 * i + 1], Y1 = ysp[2 * i + 1], Z1 = zsp[2 * i + 1];
        const v2f x0 = {X0.x, X0.y}, x1 = {X0.z, X0.w};
        const v2f x2 = {X1.x, X1.y}, x3 = {X1.z, X1.w};
        const v2f y0 = {Y0.x, Y0.y}, y1 = {Y0.z, Y0.w};
        const v2f y2 = {Y1.x, Y1.y}, y3 = {Y1.z, Y1.w};
        const v2f z0 = {Z0.x, Z0.y}, z1 = {Z0.z, Z0.w};
        const v2f z2 = {Z1.x, Z1.y}, z3 = {Z1.z, Z1.w};
        #pragma unroll
        for (int q = 0; q < QPT; ++q) {
            const v2f d0 = __builtin_elementwise_fma(
                m2x[q], x0, __builtin_elementwise_fma(m2y[q], y0, z0));
            const v2f d1 = __builtin_elementwise_fma(
                m2x[q], x1, __builtin_elementwise_fma(m2y[q], y1, z1));
            const v2f d2 = __builtin_elementwise_fma(
                m2x[q], x2, __builtin_elementwise_fma(m2y[q], y2, z2));
            const v2f d3 = __builtin_elementwise_fma(
                m2x[q], x3, __builtin_elementwise_fma(m2y[q], y3, z3));
            const float m01 = fminf(fminf(d0.x, d0.y), fminf(d1.x, d1.y));
            const float m23 = fminf(fminf(d2.x, d2.y), fminf(d3.x, d3.y));
            const float dm  = fminf(m01, m23);
            if (dm < best[q]) { best[q] = dm; bj[q] = i; }  // strict <
        }
    }

    // Exact index recovery: recompute the winning octet bit-identically
    // (zs4 re-read => identical t^2 bits) and take the FIRST in-octet index
    // whose distance equals best (descending overwrite => lowest wins).
    #pragma unroll
    for (int q = 0; q < QPT; ++q) {
        const v4f X0 = xsp[2 * bj[q]],     Y0 = ysp[2 * bj[q]],     Z0 = zsp[2 * bj[q]];
        const v4f X1 = xsp[2 * bj[q] + 1], Y1 = ysp[2 * bj[q] + 1], Z1 = zsp[2 * bj[q] + 1];
        const v2f x0 = {X0.x, X0.y}, x1 = {X0.z, X0.w};
        const v2f x2 = {X1.x, X1.y}, x3 = {X1.z, X1.w};
        const v2f y0 = {Y0.x, Y0.y}, y1 = {Y0.z, Y0.w};
        const v2f y2 = {Y1.x, Y1.y}, y3 = {Y1.z, Y1.w};
        const v2f z0 = {Z0.x, Z0.y}, z1 = {Z0.z, Z0.w};
        const v2f z2 = {Z1.x, Z1.y}, z3 = {Z1.z, Z1.w};
        const v2f d0 = __builtin_elementwise_fma(
            m2x[q], x0, __builtin_elementwise_fma(m2y[q], y0, z0));
        const v2f d1 = __builtin_elementwise_fma(
            m2x[q], x1, __builtin_elementwise_fma(m2y[q], y1, z1));
        const v2f d2 = __builtin_elementwise_fma(
            m2x[q], x2, __builtin_elementwise_fma(m2y[q], y2, z2));
        const v2f d3 = __builtin_elementwise_fma(
            m2x[q], x3, __builtin_elementwise_fma(m2y[q], y3, z3));
        int off = 7;
        if (d3.x == best[q]) off = 6;
        if (d2.y == best[q]) off = 5;
        if (d2.x == best[q]) off = 4;
        if (d1.y == best[q]) off = 3;
        if (d1.x == best[q]) off = 2;
        if (d0.y == best[q]) off = 1;
        if (d0.x == best[q]) off = 0;
        const int idx = seg * SEGLEN + 8 * bj[q] + off;
        unsigned int fb = __float_as_uint(best[q]);
        fb ^= 0x80000000u | (unsigned int)((int)fb >> 31);  // total-order map
        cand[seg * G + qslot + q * 64] =
            ((unsigned long long)fb << 32) | (unsigned int)idx;
    }
    __syncthreads();

    // First G threads: u64-min over 16 segment candidates = exact argmin.
    float val = 0.0f;
    if (threadIdx.x < G) {
        unsigned long long bp = cand[threadIdx.x];
        #pragma unroll
        for (int s = 1; s < S; ++s) {
            const unsigned long long v = cand[s * G + threadIdx.x];
            bp = v < bp ? v : bp;
        }
        const int idx = (int)(unsigned int)bp;
        const float2 qp = qb[threadIdx.x];
        const float2 tp = db[idx];            // scattered 8B, cache-hot
        float sx = 1.0f, sy = 1.0f;
        if (dir == 0) { sx = subcoef[0]; sy = subcoef[1]; }
        val = fabsf(qp.x - tp.x) * sx + fabsf(qp.y - tp.y) * sy;
    }

    // Block reduction, one atomic per block onto poisoned d_out (harmless).
    #pragma unroll
    for (int off = 32; off > 0; off >>= 1)
        val += __shfl_down(val, off, 64);
    if ((threadIdx.x & 63) == 0) ssum[threadIdx.x >> 6] = val;
    __syncthreads();
    if (threadIdx.x == 0) {
        float s = ssum[0];
        #pragma unroll
        for (int w = 1; w < BLK / 64; ++w) s += ssum[w];
        atomicAdd(out, s);   // device-scope: coherent across XCDs
    }
}

extern "C" void kernel_launch(void* const* d_in, const int* in_sizes, int n_in,
                              void* d_out, int out_size, void* d_ws, size_t ws_size,
                              hipStream_t stream) {
    const float* preds   = (const float*)d_in[0];
    const float* targs   = (const float*)d_in[1];
    const float* subcoef = (const float*)d_in[2];
    float* out = (float*)d_out;

    nn_main<<<NBLK, BLK, 0, stream>>>(preds, targs, subcoef, out);
}